// Round 1
// baseline (5870.873 us; speedup 1.0000x reference)
//
#include <hip/hip_runtime.h>
#include <stdint.h>

typedef unsigned short u16;
typedef unsigned int u32;

#define D_MODEL 1024
#define HIDDEN  4096
#define NE      8
#define NTOK    16384
#define GROUP   128
#define NGROUPS 128
#define CAP     32
#define SLOTS   32          // 31 real slots (pos 1..31 -> c=pos-1), c=31 is pad
#define ROWS_E  (NGROUPS*SLOTS)   // 4096 rows per expert (padded)

// ---------- helpers ----------
__device__ __forceinline__ u16 f2bf(float f) {
    u32 u = __float_as_uint(f);
    u32 r = (u + 0x7FFFu + ((u >> 16) & 1u)) >> 16;
    return (u16)r;
}
__device__ __forceinline__ float bf2f(u16 h) {
    return __uint_as_float(((u32)h) << 16);
}
__device__ __forceinline__ void split2(float v, u16& h, u16& l) {
    h = f2bf(v);
    float r = v - bf2f(h);
    l = f2bf(r);
}
__device__ __forceinline__ float gelu_tanh(float v) {
    float c = v * v * v;
    float inner = 0.7978845608028654f * (v + 0.044715f * c);
    return 0.5f * v * (1.0f + tanhf(inner));
}

typedef __attribute__((ext_vector_type(8))) short bf16x8;
typedef __attribute__((ext_vector_type(4))) float f32x4;

// ---------- gating ----------
// one block per group, 128 threads (one per token)
__global__ __launch_bounds__(GROUP)
void gate_kernel(const float* __restrict__ x, const float* __restrict__ gw,
                 const float* __restrict__ gb,
                 int* __restrict__ slot_tok,     // [E][G][SLOTS][2]
                 float* __restrict__ slot_gate)  // [E][G][SLOTS][2]
{
    const int g = blockIdx.x;
    const int t = threadIdx.x;
    __shared__ float sgw[D_MODEL * NE];   // 32KB
    __shared__ int   sel[GROUP][2];
    __shared__ float sg[GROUP][2];
    __shared__ int   scnt[2][NE];

    for (int i = t; i < D_MODEL * NE; i += GROUP) sgw[i] = gw[i];
    __syncthreads();

    const float* xr = x + (size_t)(g * GROUP + t) * D_MODEL;
    float lg[NE];
#pragma unroll
    for (int e = 0; e < NE; e++) lg[e] = gb[e];
    for (int d = 0; d < D_MODEL; d += 4) {
        float4 xv = *reinterpret_cast<const float4*>(xr + d);
#pragma unroll
        for (int e = 0; e < NE; e++) {
            lg[e] += xv.x * sgw[(d + 0) * NE + e] + xv.y * sgw[(d + 1) * NE + e]
                   + xv.z * sgw[(d + 2) * NE + e] + xv.w * sgw[(d + 3) * NE + e];
        }
    }
    float mx = lg[0];
#pragma unroll
    for (int e = 1; e < NE; e++) mx = fmaxf(mx, lg[e]);
    float p[NE]; float s = 0.f;
#pragma unroll
    for (int e = 0; e < NE; e++) { p[e] = expf(lg[e] - mx); s += p[e]; }
    float inv = 1.0f / s;
#pragma unroll
    for (int e = 0; e < NE; e++) p[e] *= inv;

    // top-2, ties -> lowest index (strict >)
    int e0 = 0;
#pragma unroll
    for (int e = 1; e < NE; e++) if (p[e] > p[e0]) e0 = e;
    int e1 = -1;
#pragma unroll
    for (int e = 0; e < NE; e++) {
        if (e == e0) continue;
        if (e1 < 0 || p[e] > p[e1]) e1 = e;
    }
    sel[t][0] = e0; sel[t][1] = e1;
    sg[t][0] = p[e0]; sg[t][1] = p[e1];

    // init slot arrays for this group (all experts)
    for (int i = t; i < NE * SLOTS * 2; i += GROUP) {
        int e = i / (SLOTS * 2); int rem = i % (SLOTS * 2);
        int c = rem >> 1; int k = rem & 1;
        size_t idx = ((size_t)(e * NGROUPS + g) * SLOTS + c) * 2 + k;
        slot_tok[idx] = -1;
        slot_gate[idx] = 0.f;
    }
    if (t < 2 * NE) ((int*)scnt)[t] = 0;
    __syncthreads();

    if (t == 0) {
        // serial per-(k,e) cumsum positions (matches cumsum over s per (k,e))
        for (int ss = 0; ss < GROUP; ss++) {
            for (int k = 0; k < 2; k++) {
                int e = sel[ss][k];
                int pos = ++scnt[k][e];
                if (pos < CAP) {   // pos in 1..31, slot c = pos-1
                    int c = pos - 1;
                    size_t idx = ((size_t)(e * NGROUPS + g) * SLOTS + c) * 2 + k;
                    slot_tok[idx] = ss;
                    slot_gate[idx] = sg[ss][k];
                }
            }
        }
    }
}

// ---------- GEMM (split-bf16, 3-product) ----------
// C = A @ B with A (M x K), B (K x N, row-major k-major).  M = 4096 always.
// AMODE 0: A = fp32 global, direct rows
// AMODE 1: A = gathered sum of up to 2 x-rows via slot_tok (routed GEMM1)
// AMODE 2: A = split bf16 planes (Hh/Hl)
// EPI 0: gelu -> split-store to Hh/Hl (N=HIDDEN)
// EPI 1: plain fp32 store to outp (N=D_MODEL)
// EPI 2: scatter atomicAdd gate*val to out tokens (routed GEMM2)
#define BM 128
#define BN 128
#define BK 32
#define LSTR 40   // padded LDS row stride (elements); 80B = 16B-aligned, bank-spread

template<int AMODE, int EPI>
__global__ __launch_bounds__(256)
void gemm_split(const float* __restrict__ Af,
                const u16* __restrict__ AhG, const u16* __restrict__ AlG,
                const float* __restrict__ Bf, int K, int N,
                const float* __restrict__ xg,
                const int* __restrict__ stok_g, const float* __restrict__ sgate_g,
                u16* __restrict__ Hh, u16* __restrict__ Hl,
                float* __restrict__ outp)
{
    __shared__ __align__(16) u16 sAh[BM * LSTR];
    __shared__ __align__(16) u16 sAl[BM * LSTR];
    __shared__ __align__(16) u16 sBh[BN * LSTR];
    __shared__ __align__(16) u16 sBl[BN * LSTR];
    __shared__ int   srow_tok[BM * 2];
    __shared__ float srow_gate[BM * 2];

    const int tid  = threadIdx.x;
    const int lane = tid & 63;
    const int wave = tid >> 6;
    const int wm = (wave >> 1) * 64;
    const int wn = (wave & 1) * 64;
    const int M0 = blockIdx.y * BM;
    const int N0 = blockIdx.x * BN;

    if (AMODE == 1) {
        for (int i = tid; i < BM * 2; i += 256) {
            int row = M0 + (i >> 1);
            int g = row >> 5, c = row & 31;
            srow_tok[i] = stok_g[((size_t)g * SLOTS + c) * 2 + (i & 1)];
        }
        __syncthreads();
    }

    f32x4 acc[4][4];
#pragma unroll
    for (int mi = 0; mi < 4; mi++)
#pragma unroll
        for (int ni = 0; ni < 4; ni++) {
            acc[mi][ni].x = 0.f; acc[mi][ni].y = 0.f;
            acc[mi][ni].z = 0.f; acc[mi][ni].w = 0.f;
        }

    const int ar = tid >> 1;            // A stage: row 0..127
    const int ac = (tid & 1) * 16;      // col half
    const int bk = tid >> 3;            // B stage: k 0..31
    const int bn0 = tid & 7;            // n = bn0 + 8j

    for (int k0 = 0; k0 < K; k0 += BK) {
        // ---- stage A ----
        if (AMODE == 0) {
            const float* src = Af + (size_t)(M0 + ar) * K + k0 + ac;
#pragma unroll
            for (int j = 0; j < 16; j += 4) {
                float4 v = *reinterpret_cast<const float4*>(src + j);
                float vv[4] = {v.x, v.y, v.z, v.w};
                u16 hh[4], ll[4];
#pragma unroll
                for (int q = 0; q < 4; q++) split2(vv[q], hh[q], ll[q]);
#pragma unroll
                for (int q = 0; q < 4; q += 2) {
                    *(u32*)&sAh[ar * LSTR + ac + j + q] = (u32)hh[q] | ((u32)hh[q + 1] << 16);
                    *(u32*)&sAl[ar * LSTR + ac + j + q] = (u32)ll[q] | ((u32)ll[q + 1] << 16);
                }
            }
        } else if (AMODE == 1) {
            int t0 = srow_tok[ar * 2], t1 = srow_tok[ar * 2 + 1];
            int g = (M0 + ar) >> 5;
            const float* x0 = xg + (size_t)(g * GROUP + (t0 < 0 ? 0 : t0)) * D_MODEL + k0 + ac;
            const float* x1 = xg + (size_t)(g * GROUP + (t1 < 0 ? 0 : t1)) * D_MODEL + k0 + ac;
#pragma unroll
            for (int j = 0; j < 16; j += 4) {
                float4 v0 = (t0 >= 0) ? *reinterpret_cast<const float4*>(x0 + j) : make_float4(0, 0, 0, 0);
                float4 v1 = (t1 >= 0) ? *reinterpret_cast<const float4*>(x1 + j) : make_float4(0, 0, 0, 0);
                float vv[4] = {v0.x + v1.x, v0.y + v1.y, v0.z + v1.z, v0.w + v1.w};
                u16 hh[4], ll[4];
#pragma unroll
                for (int q = 0; q < 4; q++) split2(vv[q], hh[q], ll[q]);
#pragma unroll
                for (int q = 0; q < 4; q += 2) {
                    *(u32*)&sAh[ar * LSTR + ac + j + q] = (u32)hh[q] | ((u32)hh[q + 1] << 16);
                    *(u32*)&sAl[ar * LSTR + ac + j + q] = (u32)ll[q] | ((u32)ll[q + 1] << 16);
                }
            }
        } else { // AMODE 2
            const u16* sh = AhG + (size_t)(M0 + ar) * K + k0 + ac;
            const u16* sl = AlG + (size_t)(M0 + ar) * K + k0 + ac;
            *(uint4*)&sAh[ar * LSTR + ac]     = *(const uint4*)(sh);
            *(uint4*)&sAh[ar * LSTR + ac + 8] = *(const uint4*)(sh + 8);
            *(uint4*)&sAl[ar * LSTR + ac]     = *(const uint4*)(sl);
            *(uint4*)&sAl[ar * LSTR + ac + 8] = *(const uint4*)(sl + 8);
        }
        // ---- stage B (transposed into [n][k], conflict-free b16 writes) ----
        {
            const float* src = Bf + (size_t)(k0 + bk) * N + N0 + bn0;
#pragma unroll
            for (int j = 0; j < 16; j++) {
                float v = src[8 * j];
                u16 h, l; split2(v, h, l);
                sBh[(bn0 + 8 * j) * LSTR + bk] = h;
                sBl[(bn0 + 8 * j) * LSTR + bk] = l;
            }
        }
        __syncthreads();
        // ---- compute ----
        const int fr = lane & 15;
        const int kb = (lane >> 4) * 8;
        bf16x8 ah[4], al[4], bh[4], bl[4];
#pragma unroll
        for (int mi = 0; mi < 4; mi++) {
            ah[mi] = *(const bf16x8*)&sAh[(wm + mi * 16 + fr) * LSTR + kb];
            al[mi] = *(const bf16x8*)&sAl[(wm + mi * 16 + fr) * LSTR + kb];
        }
#pragma unroll
        for (int ni = 0; ni < 4; ni++) {
            bh[ni] = *(const bf16x8*)&sBh[(wn + ni * 16 + fr) * LSTR + kb];
            bl[ni] = *(const bf16x8*)&sBl[(wn + ni * 16 + fr) * LSTR + kb];
        }
#pragma unroll
        for (int mi = 0; mi < 4; mi++)
#pragma unroll
            for (int ni = 0; ni < 4; ni++) {
                acc[mi][ni] = __builtin_amdgcn_mfma_f32_16x16x32_bf16(ah[mi], bh[ni], acc[mi][ni], 0, 0, 0);
                acc[mi][ni] = __builtin_amdgcn_mfma_f32_16x16x32_bf16(ah[mi], bl[ni], acc[mi][ni], 0, 0, 0);
                acc[mi][ni] = __builtin_amdgcn_mfma_f32_16x16x32_bf16(al[mi], bh[ni], acc[mi][ni], 0, 0, 0);
            }
        __syncthreads();
    }

    // ---- epilogue ----
    if (EPI == 2) {
        for (int i = tid; i < BM * 2; i += 256) {
            int row = M0 + (i >> 1);
            int g = row >> 5, c = row & 31;
            size_t idx = ((size_t)g * SLOTS + c) * 2 + (i & 1);
            srow_tok[i] = stok_g[idx];
            srow_gate[i] = sgate_g[idx];
        }
        __syncthreads();
    }
    const int fr = lane & 15;
    const int fq = lane >> 4;
#pragma unroll
    for (int mi = 0; mi < 4; mi++)
#pragma unroll
        for (int ni = 0; ni < 4; ni++)
#pragma unroll
            for (int r = 0; r < 4; r++) {
                int ml = wm + mi * 16 + fq * 4 + r;     // local row
                int n  = N0 + wn + ni * 16 + fr;        // global col
                float v = acc[mi][ni][r];
                if (EPI == 0) {
                    v = gelu_tanh(v);
                    u16 h, l; split2(v, h, l);
                    size_t o = (size_t)(M0 + ml) * N + n;   // N == HIDDEN
                    Hh[o] = h; Hl[o] = l;
                } else if (EPI == 1) {
                    outp[(size_t)(M0 + ml) * N + n] = v;    // N == D_MODEL
                } else {
                    int g = (M0 + ml) >> 5;
                    int t0 = srow_tok[ml * 2], t1 = srow_tok[ml * 2 + 1];
                    if (t0 >= 0)
                        atomicAdd(&outp[(size_t)(g * GROUP + t0) * D_MODEL + n], srow_gate[ml * 2] * v);
                    if (t1 >= 0)
                        atomicAdd(&outp[(size_t)(g * GROUP + t1) * D_MODEL + n], srow_gate[ml * 2 + 1] * v);
                }
            }
}

// ---------- launch ----------
extern "C" void kernel_launch(void* const* d_in, const int* in_sizes, int n_in,
                              void* d_out, int out_size, void* d_ws, size_t ws_size,
                              hipStream_t stream) {
    const float* x   = (const float*)d_in[0];
    const float* gw  = (const float*)d_in[1];
    const float* gb  = (const float*)d_in[2];
    const float* keys = (const float*)d_in[3];
    const float* vals = (const float*)d_in[4];
    const float* sk  = (const float*)d_in[5];
    const float* sv  = (const float*)d_in[6];
    float* out = (float*)d_out;

    // workspace layout (~67.6 MB total)
    char* w = (char*)d_ws;
    int* slot_tok = (int*)w;            w += (size_t)NE * NGROUPS * SLOTS * 2 * 4;
    float* slot_gate = (float*)w;       w += (size_t)NE * NGROUPS * SLOTS * 2 * 4;
    u16* Hh = (u16*)w;                  w += (size_t)ROWS_E * HIDDEN * 2;
    u16* Hl = (u16*)w;                  w += (size_t)ROWS_E * HIDDEN * 2;

    gate_kernel<<<NGROUPS, GROUP, 0, stream>>>(x, gw, gb, slot_tok, slot_gate);

    // shared expert: 4 chunks of 4096 tokens; writes every d_out element (poison-safe)
    for (int ch = 0; ch < 4; ch++) {
        const float* Axc = x + (size_t)ch * 4096 * D_MODEL;
        float* outc = out + (size_t)ch * 4096 * D_MODEL;
        gemm_split<0, 0><<<dim3(HIDDEN / BN, 4096 / BM), 256, 0, stream>>>(
            Axc, nullptr, nullptr, sk, D_MODEL, HIDDEN,
            nullptr, nullptr, nullptr, Hh, Hl, nullptr);
        gemm_split<2, 1><<<dim3(D_MODEL / BN, 4096 / BM), 256, 0, stream>>>(
            nullptr, Hh, Hl, sv, HIDDEN, D_MODEL,
            nullptr, nullptr, nullptr, nullptr, nullptr, outc);
    }
    // routed experts: per-e gather-GEMM -> H, then H @ V with atomic scatter
    for (int e = 0; e < NE; e++) {
        const int* st = slot_tok + (size_t)e * NGROUPS * SLOTS * 2;
        const float* sg = slot_gate + (size_t)e * NGROUPS * SLOTS * 2;
        gemm_split<1, 0><<<dim3(HIDDEN / BN, ROWS_E / BM), 256, 0, stream>>>(
            nullptr, nullptr, nullptr, keys + (size_t)e * D_MODEL * HIDDEN, D_MODEL, HIDDEN,
            x, st, nullptr, Hh, Hl, nullptr);
        gemm_split<2, 2><<<dim3(D_MODEL / BN, ROWS_E / BM), 256, 0, stream>>>(
            nullptr, Hh, Hl, vals + (size_t)e * HIDDEN * D_MODEL, HIDDEN, D_MODEL,
            nullptr, st, sg, nullptr, nullptr, out);
    }
}

// Round 2
// 4132.767 us; speedup vs baseline: 1.4206x; 1.4206x over previous
//
#include <hip/hip_runtime.h>
#include <stdint.h>

typedef unsigned short u16;
typedef unsigned int u32;

#define D_MODEL 1024
#define HIDDEN  4096
#define NE      8
#define NTOK    16384
#define GROUP   128
#define NGROUPS 128
#define CAP     32
#define SLOTS   32
#define ROWS_E  (NGROUPS*SLOTS)

// ---------- helpers ----------
__device__ __forceinline__ u16 f2bf(float f) {
    u32 u = __float_as_uint(f);
    u32 r = (u + 0x7FFFu + ((u >> 16) & 1u)) >> 16;
    return (u16)r;
}
__device__ __forceinline__ float bf2f(u16 h) {
    return __uint_as_float(((u32)h) << 16);
}
__device__ __forceinline__ void split2(float v, u16& h, u16& l) {
    h = f2bf(v);
    float r = v - bf2f(h);
    l = f2bf(r);
}
__device__ __forceinline__ float gelu_tanh(float v) {
    float c = v * v * v;
    float inner = 0.7978845608028654f * (v + 0.044715f * c);
    return 0.5f * v * (1.0f + tanhf(inner));
}

typedef __attribute__((ext_vector_type(8))) short bf16x8;
typedef __attribute__((ext_vector_type(4))) float f32x4;

__device__ __forceinline__ void load_lds16(const u16* g, u16* l) {
    __builtin_amdgcn_global_load_lds(
        (const __attribute__((address_space(1))) unsigned int*)(g),
        (__attribute__((address_space(3))) unsigned int*)(l),
        16, 0, 0);
}

// ---------- gating (unchanged, validated) ----------
__global__ __launch_bounds__(GROUP)
void gate_kernel(const float* __restrict__ x, const float* __restrict__ gw,
                 const float* __restrict__ gb,
                 int* __restrict__ slot_tok,     // [E][G][SLOTS][2]
                 float* __restrict__ slot_gate)  // [E][G][SLOTS][2]
{
    const int g = blockIdx.x;
    const int t = threadIdx.x;
    __shared__ float sgw[D_MODEL * NE];
    __shared__ int   sel[GROUP][2];
    __shared__ float sg[GROUP][2];
    __shared__ int   scnt[2][NE];

    for (int i = t; i < D_MODEL * NE; i += GROUP) sgw[i] = gw[i];
    __syncthreads();

    const float* xr = x + (size_t)(g * GROUP + t) * D_MODEL;
    float lg[NE];
#pragma unroll
    for (int e = 0; e < NE; e++) lg[e] = gb[e];
    for (int d = 0; d < D_MODEL; d += 4) {
        float4 xv = *reinterpret_cast<const float4*>(xr + d);
#pragma unroll
        for (int e = 0; e < NE; e++) {
            lg[e] += xv.x * sgw[(d + 0) * NE + e] + xv.y * sgw[(d + 1) * NE + e]
                   + xv.z * sgw[(d + 2) * NE + e] + xv.w * sgw[(d + 3) * NE + e];
        }
    }
    float mx = lg[0];
#pragma unroll
    for (int e = 1; e < NE; e++) mx = fmaxf(mx, lg[e]);
    float p[NE]; float s = 0.f;
#pragma unroll
    for (int e = 0; e < NE; e++) { p[e] = expf(lg[e] - mx); s += p[e]; }
    float inv = 1.0f / s;
#pragma unroll
    for (int e = 0; e < NE; e++) p[e] *= inv;

    int e0 = 0;
#pragma unroll
    for (int e = 1; e < NE; e++) if (p[e] > p[e0]) e0 = e;
    int e1 = -1;
#pragma unroll
    for (int e = 0; e < NE; e++) {
        if (e == e0) continue;
        if (e1 < 0 || p[e] > p[e1]) e1 = e;
    }
    sel[t][0] = e0; sel[t][1] = e1;
    sg[t][0] = p[e0]; sg[t][1] = p[e1];

    for (int i = t; i < NE * SLOTS * 2; i += GROUP) {
        int e = i / (SLOTS * 2); int rem = i % (SLOTS * 2);
        int c = rem >> 1; int k = rem & 1;
        size_t idx = ((size_t)(e * NGROUPS + g) * SLOTS + c) * 2 + k;
        slot_tok[idx] = -1;
        slot_gate[idx] = 0.f;
    }
    if (t < 2 * NE) ((int*)scnt)[t] = 0;
    __syncthreads();

    if (t == 0) {
        for (int ss = 0; ss < GROUP; ss++) {
            for (int k = 0; k < 2; k++) {
                int e = sel[ss][k];
                int pos = ++scnt[k][e];
                if (pos < CAP) {
                    int c = pos - 1;
                    size_t idx = ((size_t)(e * NGROUPS + g) * SLOTS + c) * 2 + k;
                    slot_tok[idx] = ss;
                    slot_gate[idx] = sg[ss][k];
                }
            }
        }
    }
}

// ---------- transform kernels (fp32 -> split-bf16, chunk-interleaved [rows][2K]) ----------
// layout: for k-chunk c (32 logical k), cols [64c..64c+31]=high, [64c+32..64c+63]=low

// x [R][1024] -> Xs [R][2048]
__global__ __launch_bounds__(256)
void split_rows(const float* __restrict__ in, u16* __restrict__ o) {
    size_t i4 = ((size_t)blockIdx.x * 256 + threadIdx.x) * 4;
    int row = (int)(i4 >> 10);
    int k = (int)(i4 & 1023);
    float4 v = *reinterpret_cast<const float4*>(in + i4);
    u16* op = o + (size_t)row * 2048 + 64 * (k >> 5) + (k & 31);
    float vv[4] = {v.x, v.y, v.z, v.w};
#pragma unroll
    for (int q = 0; q < 4; q++) { u16 h, l; split2(vv[q], h, l); op[q] = h; op[q + 32] = l; }
}

// B fp32 [K][N] -> out u16 [N][2K]  (transpose + split)
__global__ __launch_bounds__(256)
void transp_split(const float* __restrict__ B, u16* __restrict__ o, int K, int N) {
    __shared__ float t[32][33];
    const int tid = threadIdx.x;
    const int kc = blockIdx.y;
    const int n0 = blockIdx.x * 32;
#pragma unroll
    for (int it = 0; it < 4; it++) {
        int kk = it * 8 + (tid >> 5), nn = tid & 31;
        t[kk][nn] = B[(size_t)(kc * 32 + kk) * N + n0 + nn];
    }
    __syncthreads();
#pragma unroll
    for (int it = 0; it < 4; it++) {
        int nn = it * 8 + (tid >> 5), kk = tid & 31;
        float v = t[kk][nn];
        u16 h, l; split2(v, h, l);
        size_t ob = (size_t)(n0 + nn) * (2 * (size_t)K) + (size_t)kc * 64 + kk;
        o[ob] = h; o[ob + 32] = l;
    }
}

// routed A rows: gather (sum of up to 2 tokens) + split -> Ar [4096][2048]
__global__ __launch_bounds__(128)
void gather_split(const float* __restrict__ x, const int* __restrict__ st,
                  u16* __restrict__ Ar) {
    const int row = blockIdx.x;
    const int g = row >> 5, c = row & 31;
    const int t0 = st[(g * 32 + c) * 2 + 0];
    const int t1 = st[(g * 32 + c) * 2 + 1];
    const float* x0 = x + (size_t)(g * GROUP + (t0 < 0 ? 0 : t0)) * D_MODEL;
    const float* x1 = x + (size_t)(g * GROUP + (t1 < 0 ? 0 : t1)) * D_MODEL;
    u16* o = Ar + (size_t)row * 2048;
    const int t = threadIdx.x;
#pragma unroll
    for (int kk = t * 4; kk < D_MODEL; kk += 512) {
        float4 a = (t0 >= 0) ? *reinterpret_cast<const float4*>(x0 + kk) : make_float4(0, 0, 0, 0);
        float4 b = (t1 >= 0) ? *reinterpret_cast<const float4*>(x1 + kk) : make_float4(0, 0, 0, 0);
        float vv[4] = {a.x + b.x, a.y + b.y, a.z + b.z, a.w + b.w};
        u16* op = o + 64 * (kk >> 5) + (kk & 31);
#pragma unroll
        for (int q = 0; q < 4; q++) { u16 h, l; split2(vv[q], h, l); op[q] = h; op[q + 32] = l; }
    }
}

// ---------- uniform fast GEMM (m97 structure, split-bf16 3-product) ----------
// A [M][2K] split-interleaved, B [N][2K] split-interleaved (B^T). 128x128 tile, 4 waves.
// EPI 0: gelu -> split-store Ho [M][2N]; EPI 1: fp32 store outp [M][N];
// EPI 2: atomic scatter with gates.
template<int EPI>
__global__ __launch_bounds__(256)
void gemm_bt(const u16* __restrict__ As, const u16* __restrict__ Bs,
             const int K2, const int N,
             u16* __restrict__ Ho, float* __restrict__ outp,
             const int* __restrict__ stok, const float* __restrict__ sgate)
{
    __shared__ __align__(16) u16 smA[128 * 64];
    __shared__ __align__(16) u16 smB[128 * 64];
    __shared__ int   srow_tok[256];
    __shared__ float srow_gate[256];

    const int tid = threadIdx.x;
    const int lane = tid & 63;
    const int wv = tid >> 6;
    const int wm = (wv >> 1) * 64;
    const int wn = (wv & 1) * 64;

    // XCD-aware bijective swizzle (nwg is always a multiple of 8 here)
    const int nwg = gridDim.x * gridDim.y;
    int bid = blockIdx.y * gridDim.x + blockIdx.x;
    bid = (bid & 7) * (nwg >> 3) + (bid >> 3);
    const int M0 = (bid / gridDim.x) * 128;
    const int N0 = (bid % gridDim.x) * 128;

    f32x4 acc[4][4];
#pragma unroll
    for (int mi = 0; mi < 4; mi++)
#pragma unroll
        for (int ni = 0; ni < 4; ni++) {
            acc[mi][ni].x = 0.f; acc[mi][ni].y = 0.f;
            acc[mi][ni].z = 0.f; acc[mi][ni].w = 0.f;
        }

    const int stg_r = lane >> 3;
    const int stg_c = (lane & 7) * 8;
    const int fr = lane & 15;
    const int kb = (lane >> 4) * 8;

    const int nch = K2 >> 6;
    for (int kc = 0; kc < nch; kc++) {
        const u16* gA = As + (size_t)M0 * K2 + (size_t)kc * 64;
        const u16* gB = Bs + (size_t)N0 * K2 + (size_t)kc * 64;
#pragma unroll
        for (int i = 0; i < 4; i++) {
            const int ins = wv * 4 + i;           // 16 x 1KB instructions per tile
            const int rr = ins * 8 + stg_r;
            load_lds16(gA + (size_t)rr * K2 + stg_c, &smA[ins * 512]);
            load_lds16(gB + (size_t)rr * K2 + stg_c, &smB[ins * 512]);
        }
        __syncthreads();

        bf16x8 ah[4], al[4], bh[4], bl[4];
#pragma unroll
        for (int mi = 0; mi < 4; mi++) {
            ah[mi] = *(const bf16x8*)&smA[(wm + mi * 16 + fr) * 64 + kb];
            al[mi] = *(const bf16x8*)&smA[(wm + mi * 16 + fr) * 64 + 32 + kb];
        }
#pragma unroll
        for (int ni = 0; ni < 4; ni++) {
            bh[ni] = *(const bf16x8*)&smB[(wn + ni * 16 + fr) * 64 + kb];
            bl[ni] = *(const bf16x8*)&smB[(wn + ni * 16 + fr) * 64 + 32 + kb];
        }
#pragma unroll
        for (int mi = 0; mi < 4; mi++)
#pragma unroll
            for (int ni = 0; ni < 4; ni++) {
                acc[mi][ni] = __builtin_amdgcn_mfma_f32_16x16x32_bf16(ah[mi], bh[ni], acc[mi][ni], 0, 0, 0);
                acc[mi][ni] = __builtin_amdgcn_mfma_f32_16x16x32_bf16(ah[mi], bl[ni], acc[mi][ni], 0, 0, 0);
                acc[mi][ni] = __builtin_amdgcn_mfma_f32_16x16x32_bf16(al[mi], bh[ni], acc[mi][ni], 0, 0, 0);
            }
        __syncthreads();
    }

    if (EPI == 2) {
        const int rowl = tid >> 1;
        const int row = M0 + rowl;
        const int g = row >> 5, c = row & 31;
        size_t idx = ((size_t)g * SLOTS + c) * 2 + (tid & 1);
        srow_tok[tid] = stok[idx];
        srow_gate[tid] = sgate[idx];
        __syncthreads();
    }
    const int fq = lane >> 4;
#pragma unroll
    for (int mi = 0; mi < 4; mi++)
#pragma unroll
        for (int ni = 0; ni < 4; ni++)
#pragma unroll
            for (int r = 0; r < 4; r++) {
                int ml = wm + mi * 16 + fq * 4 + r;
                int n = N0 + wn + ni * 16 + fr;
                float v = acc[mi][ni][r];
                if (EPI == 0) {
                    v = gelu_tanh(v);
                    u16 h, l; split2(v, h, l);
                    size_t o = (size_t)(M0 + ml) * (2 * (size_t)N) + 64 * (n >> 5) + (n & 31);
                    Ho[o] = h; Ho[o + 32] = l;
                } else if (EPI == 1) {
                    outp[(size_t)(M0 + ml) * N + n] = v;
                } else {
                    int g = (M0 + ml) >> 5;
                    int t0 = srow_tok[ml * 2], t1 = srow_tok[ml * 2 + 1];
                    if (t0 >= 0)
                        atomicAdd(&outp[(size_t)(g * GROUP + t0) * D_MODEL + n], srow_gate[ml * 2] * v);
                    if (t1 >= 0)
                        atomicAdd(&outp[(size_t)(g * GROUP + t1) * D_MODEL + n], srow_gate[ml * 2 + 1] * v);
                }
            }
}

// ---------- fallback GEMM (round-1, validated) ----------
#define BM 128
#define BN 128
#define BK 32
#define LSTR 40

template<int AMODE, int EPI>
__global__ __launch_bounds__(256)
void gemm_split(const float* __restrict__ Af,
                const u16* __restrict__ AhG, const u16* __restrict__ AlG,
                const float* __restrict__ Bf, int K, int N,
                const float* __restrict__ xg,
                const int* __restrict__ stok_g, const float* __restrict__ sgate_g,
                u16* __restrict__ Hh, u16* __restrict__ Hl,
                float* __restrict__ outp)
{
    __shared__ __align__(16) u16 sAh[BM * LSTR];
    __shared__ __align__(16) u16 sAl[BM * LSTR];
    __shared__ __align__(16) u16 sBh[BN * LSTR];
    __shared__ __align__(16) u16 sBl[BN * LSTR];
    __shared__ int   srow_tok[BM * 2];
    __shared__ float srow_gate[BM * 2];

    const int tid  = threadIdx.x;
    const int lane = tid & 63;
    const int wave = tid >> 6;
    const int wm = (wave >> 1) * 64;
    const int wn = (wave & 1) * 64;
    const int M0 = blockIdx.y * BM;
    const int N0 = blockIdx.x * BN;

    if (AMODE == 1) {
        for (int i = tid; i < BM * 2; i += 256) {
            int row = M0 + (i >> 1);
            int g = row >> 5, c = row & 31;
            srow_tok[i] = stok_g[((size_t)g * SLOTS + c) * 2 + (i & 1)];
        }
        __syncthreads();
    }

    f32x4 acc[4][4];
#pragma unroll
    for (int mi = 0; mi < 4; mi++)
#pragma unroll
        for (int ni = 0; ni < 4; ni++) {
            acc[mi][ni].x = 0.f; acc[mi][ni].y = 0.f;
            acc[mi][ni].z = 0.f; acc[mi][ni].w = 0.f;
        }

    const int ar = tid >> 1;
    const int ac = (tid & 1) * 16;
    const int bk = tid >> 3;
    const int bn0 = tid & 7;

    for (int k0 = 0; k0 < K; k0 += BK) {
        if (AMODE == 0) {
            const float* src = Af + (size_t)(M0 + ar) * K + k0 + ac;
#pragma unroll
            for (int j = 0; j < 16; j += 4) {
                float4 v = *reinterpret_cast<const float4*>(src + j);
                float vv[4] = {v.x, v.y, v.z, v.w};
                u16 hh[4], ll[4];
#pragma unroll
                for (int q = 0; q < 4; q++) split2(vv[q], hh[q], ll[q]);
#pragma unroll
                for (int q = 0; q < 4; q += 2) {
                    *(u32*)&sAh[ar * LSTR + ac + j + q] = (u32)hh[q] | ((u32)hh[q + 1] << 16);
                    *(u32*)&sAl[ar * LSTR + ac + j + q] = (u32)ll[q] | ((u32)ll[q + 1] << 16);
                }
            }
        } else if (AMODE == 1) {
            int t0 = srow_tok[ar * 2], t1 = srow_tok[ar * 2 + 1];
            int g = (M0 + ar) >> 5;
            const float* x0 = xg + (size_t)(g * GROUP + (t0 < 0 ? 0 : t0)) * D_MODEL + k0 + ac;
            const float* x1 = xg + (size_t)(g * GROUP + (t1 < 0 ? 0 : t1)) * D_MODEL + k0 + ac;
#pragma unroll
            for (int j = 0; j < 16; j += 4) {
                float4 v0 = (t0 >= 0) ? *reinterpret_cast<const float4*>(x0 + j) : make_float4(0, 0, 0, 0);
                float4 v1 = (t1 >= 0) ? *reinterpret_cast<const float4*>(x1 + j) : make_float4(0, 0, 0, 0);
                float vv[4] = {v0.x + v1.x, v0.y + v1.y, v0.z + v1.z, v0.w + v1.w};
                u16 hh[4], ll[4];
#pragma unroll
                for (int q = 0; q < 4; q++) split2(vv[q], hh[q], ll[q]);
#pragma unroll
                for (int q = 0; q < 4; q += 2) {
                    *(u32*)&sAh[ar * LSTR + ac + j + q] = (u32)hh[q] | ((u32)hh[q + 1] << 16);
                    *(u32*)&sAl[ar * LSTR + ac + j + q] = (u32)ll[q] | ((u32)ll[q + 1] << 16);
                }
            }
        } else {
            const u16* sh = AhG + (size_t)(M0 + ar) * K + k0 + ac;
            const u16* sl = AlG + (size_t)(M0 + ar) * K + k0 + ac;
            *(uint4*)&sAh[ar * LSTR + ac]     = *(const uint4*)(sh);
            *(uint4*)&sAh[ar * LSTR + ac + 8] = *(const uint4*)(sh + 8);
            *(uint4*)&sAl[ar * LSTR + ac]     = *(const uint4*)(sl);
            *(uint4*)&sAl[ar * LSTR + ac + 8] = *(const uint4*)(sl + 8);
        }
        {
            const float* src = Bf + (size_t)(k0 + bk) * N + N0 + bn0;
#pragma unroll
            for (int j = 0; j < 16; j++) {
                float v = src[8 * j];
                u16 h, l; split2(v, h, l);
                sBh[(bn0 + 8 * j) * LSTR + bk] = h;
                sBl[(bn0 + 8 * j) * LSTR + bk] = l;
            }
        }
        __syncthreads();
        const int fr = lane & 15;
        const int kb = (lane >> 4) * 8;
        bf16x8 ah[4], al[4], bh[4], bl[4];
#pragma unroll
        for (int mi = 0; mi < 4; mi++) {
            ah[mi] = *(const bf16x8*)&sAh[(wm + mi * 16 + fr) * LSTR + kb];
            al[mi] = *(const bf16x8*)&sAl[(wm + mi * 16 + fr) * LSTR + kb];
        }
#pragma unroll
        for (int ni = 0; ni < 4; ni++) {
            bh[ni] = *(const bf16x8*)&sBh[(wn + ni * 16 + fr) * LSTR + kb];
            bl[ni] = *(const bf16x8*)&sBl[(wn + ni * 16 + fr) * LSTR + kb];
        }
#pragma unroll
        for (int mi = 0; mi < 4; mi++)
#pragma unroll
            for (int ni = 0; ni < 4; ni++) {
                acc[mi][ni] = __builtin_amdgcn_mfma_f32_16x16x32_bf16(ah[mi], bh[ni], acc[mi][ni], 0, 0, 0);
                acc[mi][ni] = __builtin_amdgcn_mfma_f32_16x16x32_bf16(ah[mi], bl[ni], acc[mi][ni], 0, 0, 0);
                acc[mi][ni] = __builtin_amdgcn_mfma_f32_16x16x32_bf16(al[mi], bh[ni], acc[mi][ni], 0, 0, 0);
            }
        __syncthreads();
    }

    if (EPI == 2) {
        for (int i = tid; i < BM * 2; i += 256) {
            int row = M0 + (i >> 1);
            int g = row >> 5, c = row & 31;
            size_t idx = ((size_t)g * SLOTS + c) * 2 + (i & 1);
            srow_tok[i] = stok_g[idx];
            srow_gate[i] = sgate_g[idx];
        }
        __syncthreads();
    }
    const int fr = lane & 15;
    const int fq = lane >> 4;
#pragma unroll
    for (int mi = 0; mi < 4; mi++)
#pragma unroll
        for (int ni = 0; ni < 4; ni++)
#pragma unroll
            for (int r = 0; r < 4; r++) {
                int ml = wm + mi * 16 + fq * 4 + r;
                int n  = N0 + wn + ni * 16 + fr;
                float v = acc[mi][ni][r];
                if (EPI == 0) {
                    v = gelu_tanh(v);
                    u16 h, l; split2(v, h, l);
                    size_t o = (size_t)(M0 + ml) * N + n;
                    Hh[o] = h; Hl[o] = l;
                } else if (EPI == 1) {
                    outp[(size_t)(M0 + ml) * N + n] = v;
                } else {
                    int g = (M0 + ml) >> 5;
                    int t0 = srow_tok[ml * 2], t1 = srow_tok[ml * 2 + 1];
                    if (t0 >= 0)
                        atomicAdd(&outp[(size_t)(g * GROUP + t0) * D_MODEL + n], srow_gate[ml * 2] * v);
                    if (t1 >= 0)
                        atomicAdd(&outp[(size_t)(g * GROUP + t1) * D_MODEL + n], srow_gate[ml * 2 + 1] * v);
                }
            }
}

// ---------- launch ----------
extern "C" void kernel_launch(void* const* d_in, const int* in_sizes, int n_in,
                              void* d_out, int out_size, void* d_ws, size_t ws_size,
                              hipStream_t stream) {
    const float* x    = (const float*)d_in[0];
    const float* gw   = (const float*)d_in[1];
    const float* gb   = (const float*)d_in[2];
    const float* keys = (const float*)d_in[3];
    const float* vals = (const float*)d_in[4];
    const float* sk   = (const float*)d_in[5];
    const float* sv   = (const float*)d_in[6];
    float* out = (float*)d_out;

    const size_t SLOT_BYTES = (size_t)NE * NGROUPS * SLOTS * 2 * 4;   // 262144 each
    const size_t NEED_FAST = 2 * SLOT_BYTES
                           + (size_t)NTOK * 2048 * 2                  // Xs   67MB
                           + (size_t)ROWS_E * 8192 * 2                // Hs   67MB
                           + (size_t)HIDDEN * 2048 * 2                // SKs  16.8MB
                           + (size_t)D_MODEL * 8192 * 2               // SVs  16.8MB
                           + (size_t)ROWS_E * 2048 * 2                // Ks_e
                           + (size_t)D_MODEL * 8192 * 2               // Vs_e
                           + (size_t)ROWS_E * 2048 * 2;               // Ar_e

    if (ws_size >= NEED_FAST) {
        char* w = (char*)d_ws;
        int*   slot_tok  = (int*)w;   w += SLOT_BYTES;
        float* slot_gate = (float*)w; w += SLOT_BYTES;
        u16* Xs   = (u16*)w; w += (size_t)NTOK * 2048 * 2;
        u16* Hs   = (u16*)w; w += (size_t)ROWS_E * 8192 * 2;
        u16* SKs  = (u16*)w; w += (size_t)HIDDEN * 2048 * 2;
        u16* SVs  = (u16*)w; w += (size_t)D_MODEL * 8192 * 2;
        u16* Ks_e = (u16*)w; w += (size_t)ROWS_E * 2048 * 2;
        u16* Vs_e = (u16*)w; w += (size_t)D_MODEL * 8192 * 2;
        u16* Ar_e = (u16*)w; w += (size_t)ROWS_E * 2048 * 2;

        gate_kernel<<<NGROUPS, GROUP, 0, stream>>>(x, gw, gb, slot_tok, slot_gate);
        split_rows<<<NTOK * D_MODEL / 1024, 256, 0, stream>>>(x, Xs);
        transp_split<<<dim3(HIDDEN / 32, D_MODEL / 32), 256, 0, stream>>>(sk, SKs, D_MODEL, HIDDEN);
        transp_split<<<dim3(D_MODEL / 32, HIDDEN / 32), 256, 0, stream>>>(sv, SVs, HIDDEN, D_MODEL);

        for (int ch = 0; ch < 4; ch++) {
            gemm_bt<0><<<dim3(HIDDEN / 128, 32), 256, 0, stream>>>(
                Xs + (size_t)ch * 4096 * 2048, SKs, 2048, HIDDEN, Hs, nullptr, nullptr, nullptr);
            gemm_bt<1><<<dim3(D_MODEL / 128, 32), 256, 0, stream>>>(
                Hs, SVs, 8192, D_MODEL, nullptr, out + (size_t)ch * 4096 * D_MODEL, nullptr, nullptr);
        }
        for (int e = 0; e < NE; e++) {
            const int* st = slot_tok + (size_t)e * NGROUPS * SLOTS * 2;
            const float* sg = slot_gate + (size_t)e * NGROUPS * SLOTS * 2;
            gather_split<<<ROWS_E, 128, 0, stream>>>(x, st, Ar_e);
            transp_split<<<dim3(HIDDEN / 32, D_MODEL / 32), 256, 0, stream>>>(
                keys + (size_t)e * D_MODEL * HIDDEN, Ks_e, D_MODEL, HIDDEN);
            transp_split<<<dim3(D_MODEL / 32, HIDDEN / 32), 256, 0, stream>>>(
                vals + (size_t)e * HIDDEN * D_MODEL, Vs_e, HIDDEN, D_MODEL);
            gemm_bt<0><<<dim3(HIDDEN / 128, 32), 256, 0, stream>>>(
                Ar_e, Ks_e, 2048, HIDDEN, Hs, nullptr, nullptr, nullptr);
            gemm_bt<2><<<dim3(D_MODEL / 128, 32), 256, 0, stream>>>(
                Hs, Vs_e, 8192, D_MODEL, nullptr, out, st, sg);
        }
    } else {
        // fallback: round-1 path (needs ~135MB)
        char* w = (char*)d_ws;
        int* slot_tok = (int*)w;      w += SLOT_BYTES;
        float* slot_gate = (float*)w; w += SLOT_BYTES;
        u16* Hh = (u16*)w;            w += (size_t)ROWS_E * HIDDEN * 2;
        u16* Hl = (u16*)w;            w += (size_t)ROWS_E * HIDDEN * 2;

        gate_kernel<<<NGROUPS, GROUP, 0, stream>>>(x, gw, gb, slot_tok, slot_gate);
        for (int ch = 0; ch < 4; ch++) {
            const float* Axc = x + (size_t)ch * 4096 * D_MODEL;
            float* outc = out + (size_t)ch * 4096 * D_MODEL;
            gemm_split<0, 0><<<dim3(HIDDEN / BN, 4096 / BM), 256, 0, stream>>>(
                Axc, nullptr, nullptr, sk, D_MODEL, HIDDEN,
                nullptr, nullptr, nullptr, Hh, Hl, nullptr);
            gemm_split<2, 1><<<dim3(D_MODEL / BN, 4096 / BM), 256, 0, stream>>>(
                nullptr, Hh, Hl, sv, HIDDEN, D_MODEL,
                nullptr, nullptr, nullptr, nullptr, nullptr, outc);
        }
        for (int e = 0; e < NE; e++) {
            const int* st = slot_tok + (size_t)e * NGROUPS * SLOTS * 2;
            const float* sg = slot_gate + (size_t)e * NGROUPS * SLOTS * 2;
            gemm_split<1, 0><<<dim3(HIDDEN / BN, ROWS_E / BM), 256, 0, stream>>>(
                nullptr, nullptr, nullptr, keys + (size_t)e * D_MODEL * HIDDEN, D_MODEL, HIDDEN,
                x, st, nullptr, Hh, Hl, nullptr);
            gemm_split<2, 2><<<dim3(D_MODEL / BN, ROWS_E / BM), 256, 0, stream>>>(
                nullptr, Hh, Hl, vals + (size_t)e * HIDDEN * D_MODEL, HIDDEN, D_MODEL,
                nullptr, st, sg, nullptr, nullptr, out);
        }
    }
}

// Round 3
// 1795.394 us; speedup vs baseline: 3.2700x; 2.3019x over previous
//
#include <hip/hip_runtime.h>
#include <stdint.h>

typedef unsigned short u16;
typedef unsigned int u32;

#define D_MODEL 1024
#define HIDDEN  4096
#define NE      8
#define NTOK    16384
#define GROUP   128
#define NGROUPS 128
#define CAP     32
#define SLOTS   32
#define ROWS_E  (NGROUPS*SLOTS)

// ---------- helpers ----------
__device__ __forceinline__ u16 f2bf(float f) {
    u32 u = __float_as_uint(f);
    u32 r = (u + 0x7FFFu + ((u >> 16) & 1u)) >> 16;
    return (u16)r;
}
__device__ __forceinline__ float bf2f(u16 h) {
    return __uint_as_float(((u32)h) << 16);
}
__device__ __forceinline__ void split2(float v, u16& h, u16& l) {
    h = f2bf(v);
    float r = v - bf2f(h);
    l = f2bf(r);
}
__device__ __forceinline__ float gelu_tanh(float v) {
    float c = v * v * v;
    float inner = 0.7978845608028654f * (v + 0.044715f * c);
    return 0.5f * v * (1.0f + tanhf(inner));
}

typedef __attribute__((ext_vector_type(8))) short bf16x8;
typedef __attribute__((ext_vector_type(4))) float f32x4;

__device__ __forceinline__ void load_lds16(const u16* g, u16* l) {
    __builtin_amdgcn_global_load_lds(
        (const __attribute__((address_space(1))) unsigned int*)(g),
        (__attribute__((address_space(3))) unsigned int*)(l),
        16, 0, 0);
}

// ---------- gating (unchanged, validated) ----------
__global__ __launch_bounds__(GROUP)
void gate_kernel(const float* __restrict__ x, const float* __restrict__ gw,
                 const float* __restrict__ gb,
                 int* __restrict__ slot_tok,     // [E][G][SLOTS][2]
                 float* __restrict__ slot_gate)  // [E][G][SLOTS][2]
{
    const int g = blockIdx.x;
    const int t = threadIdx.x;
    __shared__ float sgw[D_MODEL * NE];
    __shared__ int   sel[GROUP][2];
    __shared__ float sg[GROUP][2];
    __shared__ int   scnt[2][NE];

    for (int i = t; i < D_MODEL * NE; i += GROUP) sgw[i] = gw[i];
    __syncthreads();

    const float* xr = x + (size_t)(g * GROUP + t) * D_MODEL;
    float lg[NE];
#pragma unroll
    for (int e = 0; e < NE; e++) lg[e] = gb[e];
    for (int d = 0; d < D_MODEL; d += 4) {
        float4 xv = *reinterpret_cast<const float4*>(xr + d);
#pragma unroll
        for (int e = 0; e < NE; e++) {
            lg[e] += xv.x * sgw[(d + 0) * NE + e] + xv.y * sgw[(d + 1) * NE + e]
                   + xv.z * sgw[(d + 2) * NE + e] + xv.w * sgw[(d + 3) * NE + e];
        }
    }
    float mx = lg[0];
#pragma unroll
    for (int e = 1; e < NE; e++) mx = fmaxf(mx, lg[e]);
    float p[NE]; float s = 0.f;
#pragma unroll
    for (int e = 0; e < NE; e++) { p[e] = expf(lg[e] - mx); s += p[e]; }
    float inv = 1.0f / s;
#pragma unroll
    for (int e = 0; e < NE; e++) p[e] *= inv;

    int e0 = 0;
#pragma unroll
    for (int e = 1; e < NE; e++) if (p[e] > p[e0]) e0 = e;
    int e1 = -1;
#pragma unroll
    for (int e = 0; e < NE; e++) {
        if (e == e0) continue;
        if (e1 < 0 || p[e] > p[e1]) e1 = e;
    }
    sel[t][0] = e0; sel[t][1] = e1;
    sg[t][0] = p[e0]; sg[t][1] = p[e1];

    for (int i = t; i < NE * SLOTS * 2; i += GROUP) {
        int e = i / (SLOTS * 2); int rem = i % (SLOTS * 2);
        int c = rem >> 1; int k = rem & 1;
        size_t idx = ((size_t)(e * NGROUPS + g) * SLOTS + c) * 2 + k;
        slot_tok[idx] = -1;
        slot_gate[idx] = 0.f;
    }
    if (t < 2 * NE) ((int*)scnt)[t] = 0;
    __syncthreads();

    if (t == 0) {
        for (int ss = 0; ss < GROUP; ss++) {
            for (int k = 0; k < 2; k++) {
                int e = sel[ss][k];
                int pos = ++scnt[k][e];
                if (pos < CAP) {
                    int c = pos - 1;
                    size_t idx = ((size_t)(e * NGROUPS + g) * SLOTS + c) * 2 + k;
                    slot_tok[idx] = ss;
                    slot_gate[idx] = sg[ss][k];
                }
            }
        }
    }
}

// ---------- transforms (fp32 -> plain bf16) ----------

// rows cast: fp32[R*K] -> bf16[R*K], 8 els/thread
__global__ __launch_bounds__(256)
void cast_rows(const float* __restrict__ in, u16* __restrict__ o) {
    size_t i8 = ((size_t)blockIdx.x * 256 + threadIdx.x) * 8;
    float4 a = *reinterpret_cast<const float4*>(in + i8);
    float4 b = *reinterpret_cast<const float4*>(in + i8 + 4);
    u16 r[8];
    r[0] = f2bf(a.x); r[1] = f2bf(a.y); r[2] = f2bf(a.z); r[3] = f2bf(a.w);
    r[4] = f2bf(b.x); r[5] = f2bf(b.y); r[6] = f2bf(b.z); r[7] = f2bf(b.w);
    *reinterpret_cast<uint4*>(o + i8) = *reinterpret_cast<uint4*>(r);
}

// B fp32 [K][N] -> bf16 [N][K] (transpose + cast)
__global__ __launch_bounds__(256)
void transp_cast(const float* __restrict__ B, u16* __restrict__ o, int K, int N) {
    __shared__ float t[32][33];
    const int tid = threadIdx.x;
    const int kc = blockIdx.y;
    const int n0 = blockIdx.x * 32;
#pragma unroll
    for (int it = 0; it < 4; it++) {
        int kk = it * 8 + (tid >> 5), nn = tid & 31;
        t[kk][nn] = B[(size_t)(kc * 32 + kk) * N + n0 + nn];
    }
    __syncthreads();
#pragma unroll
    for (int it = 0; it < 4; it++) {
        int nn = it * 8 + (tid >> 5), kk = tid & 31;
        o[(size_t)(n0 + nn) * K + kc * 32 + kk] = f2bf(t[kk][nn]);
    }
}

// routed A rows: gather (sum of up to 2 tokens) -> bf16 Ar [4096][1024]
__global__ __launch_bounds__(128)
void gather_cast(const float* __restrict__ x, const int* __restrict__ st,
                 u16* __restrict__ Ar) {
    const int row = blockIdx.x;
    const int g = row >> 5, c = row & 31;
    const int t0 = st[(g * 32 + c) * 2 + 0];
    const int t1 = st[(g * 32 + c) * 2 + 1];
    const float* x0 = x + (size_t)(g * GROUP + (t0 < 0 ? 0 : t0)) * D_MODEL;
    const float* x1 = x + (size_t)(g * GROUP + (t1 < 0 ? 0 : t1)) * D_MODEL;
    u16* o = Ar + (size_t)row * D_MODEL;
    const int kk = threadIdx.x * 8;
    float4 a0 = (t0 >= 0) ? *reinterpret_cast<const float4*>(x0 + kk) : make_float4(0, 0, 0, 0);
    float4 a1 = (t0 >= 0) ? *reinterpret_cast<const float4*>(x0 + kk + 4) : make_float4(0, 0, 0, 0);
    float4 b0 = (t1 >= 0) ? *reinterpret_cast<const float4*>(x1 + kk) : make_float4(0, 0, 0, 0);
    float4 b1 = (t1 >= 0) ? *reinterpret_cast<const float4*>(x1 + kk + 4) : make_float4(0, 0, 0, 0);
    u16 r[8];
    r[0] = f2bf(a0.x + b0.x); r[1] = f2bf(a0.y + b0.y);
    r[2] = f2bf(a0.z + b0.z); r[3] = f2bf(a0.w + b0.w);
    r[4] = f2bf(a1.x + b1.x); r[5] = f2bf(a1.y + b1.y);
    r[6] = f2bf(a1.z + b1.z); r[7] = f2bf(a1.w + b1.w);
    *reinterpret_cast<uint4*>(o + kk) = *reinterpret_cast<uint4*>(r);
}

// ---------- plain-bf16 GEMM: 128x128 tile, BK=64, 2-phase dbuf, XOR-swizzled LDS ----------
// A [M][K] bf16 row-major, B [N][K] bf16 row-major (B^T). K multiple of 64.
// Swizzle (rule #21 both-sides): LDS element (row, e) holds global col (e ^ ((row&7)<<3)).
// Stage: linear LDS dest, inverse-swizzled global source. Read: swizzled ds_read addr.
// EPI 0: gelu -> bf16 store Ho[M][N]; EPI 1: fp32 store outp; EPI 2: atomic scatter.
template<int EPI, int KSPLIT>
__global__ __launch_bounds__(256)
void gemm_bf16(const u16* __restrict__ As, const u16* __restrict__ Bs,
               const int K, const int N,
               u16* __restrict__ Ho, float* __restrict__ outp,
               const int* __restrict__ stok, const float* __restrict__ sgate)
{
    __shared__ __align__(16) u16 smA[2][128 * 64];
    __shared__ __align__(16) u16 smB[2][128 * 64];
    __shared__ int   srow_tok[256];
    __shared__ float srow_gate[256];

    const int tid = threadIdx.x;
    const int lane = tid & 63;
    const int wv = tid >> 6;
    const int wm = (wv >> 1) * 64;
    const int wn = (wv & 1) * 64;

    // XCD-aware bijective swizzle over x*y (all grids here are multiples of 8)
    const int nwg = gridDim.x * gridDim.y;
    int bid = blockIdx.y * gridDim.x + blockIdx.x;
    bid = (bid & 7) * (nwg >> 3) + (bid >> 3);
    const int M0 = (bid / gridDim.x) * 128;
    const int N0 = (bid % gridDim.x) * 128;
    const int k0 = (KSPLIT > 1) ? blockIdx.z * (K / KSPLIT) : 0;
    const int nch = (K / KSPLIT) >> 6;   // chunks of 64

    f32x4 acc[4][4];
#pragma unroll
    for (int mi = 0; mi < 4; mi++)
#pragma unroll
        for (int ni = 0; ni < 4; ni++) {
            acc[mi][ni].x = 0.f; acc[mi][ni].y = 0.f;
            acc[mi][ni].z = 0.f; acc[mi][ni].w = 0.f;
        }

    const int r8 = lane >> 3;        // staging: row within 8-row slab
    const int c8 = lane & 7;         // staging: 16B slot index
    const int fr = lane & 15;        // frag row
    const int kb = (lane >> 4) * 8;  // frag k-offset

    const u16* gA = As + (size_t)M0 * K + k0;
    const u16* gB = Bs + (size_t)N0 * K + k0;

    // stage one 128x64 chunk pair into buf
#define STAGE(buf, kc)                                                              \
    {                                                                               \
        const u16* bA = gA + (size_t)(kc) * 64;                                     \
        const u16* bB = gB + (size_t)(kc) * 64;                                     \
        _Pragma("unroll")                                                           \
        for (int i = 0; i < 4; i++) {                                               \
            int row = wv * 32 + i * 8 + r8;                                         \
            int sc = (c8 ^ (row & 7)) * 8;                                          \
            load_lds16(bA + (size_t)row * K + sc, &smA[buf][(wv * 32 + i * 8) * 64]); \
            load_lds16(bB + (size_t)row * K + sc, &smB[buf][(wv * 32 + i * 8) * 64]); \
        }                                                                           \
    }

    STAGE(0, 0)
    __syncthreads();

    for (int kc = 0; kc < nch; kc++) {
        const int cur = kc & 1;
        if (kc + 1 < nch) STAGE(cur ^ 1, kc + 1)

#pragma unroll
        for (int s = 0; s < 2; s++) {
            bf16x8 a[4], b[4];
#pragma unroll
            for (int mi = 0; mi < 4; mi++) {
                int row = wm + mi * 16 + fr;
                a[mi] = *(const bf16x8*)&smA[cur][row * 64 + ((s * 32 + kb) ^ ((row & 7) << 3))];
            }
#pragma unroll
            for (int ni = 0; ni < 4; ni++) {
                int row = wn + ni * 16 + fr;
                b[ni] = *(const bf16x8*)&smB[cur][row * 64 + ((s * 32 + kb) ^ ((row & 7) << 3))];
            }
#pragma unroll
            for (int mi = 0; mi < 4; mi++)
#pragma unroll
                for (int ni = 0; ni < 4; ni++)
                    acc[mi][ni] = __builtin_amdgcn_mfma_f32_16x16x32_bf16(a[mi], b[ni], acc[mi][ni], 0, 0, 0);
        }
        __syncthreads();
    }
#undef STAGE

    if (EPI == 2) {
        const int row = M0 + (tid >> 1);
        const int g = row >> 5, c = row & 31;
        size_t idx = ((size_t)g * SLOTS + c) * 2 + (tid & 1);
        srow_tok[tid] = stok[idx];
        srow_gate[tid] = sgate[idx];
        __syncthreads();
    }
    const int fq = lane >> 4;
#pragma unroll
    for (int mi = 0; mi < 4; mi++)
#pragma unroll
        for (int ni = 0; ni < 4; ni++)
#pragma unroll
            for (int r = 0; r < 4; r++) {
                int ml = wm + mi * 16 + fq * 4 + r;
                int n = N0 + wn + ni * 16 + fr;
                float v = acc[mi][ni][r];
                if (EPI == 0) {
                    Ho[(size_t)(M0 + ml) * N + n] = f2bf(gelu_tanh(v));
                } else if (EPI == 1) {
                    outp[(size_t)(M0 + ml) * N + n] = v;
                } else {
                    int g = (M0 + ml) >> 5;
                    int t0 = srow_tok[ml * 2], t1 = srow_tok[ml * 2 + 1];
                    if (t0 >= 0)
                        atomicAdd(&outp[(size_t)(g * GROUP + t0) * D_MODEL + n], srow_gate[ml * 2] * v);
                    if (t1 >= 0)
                        atomicAdd(&outp[(size_t)(g * GROUP + t1) * D_MODEL + n], srow_gate[ml * 2 + 1] * v);
                }
            }
}

// ---------- fallback GEMM (round-1, validated; used only if ws too small) ----------
#define BM 128
#define BN 128
#define BK 32
#define LSTR 40

template<int AMODE, int EPI>
__global__ __launch_bounds__(256)
void gemm_split(const float* __restrict__ Af,
                const u16* __restrict__ AhG, const u16* __restrict__ AlG,
                const float* __restrict__ Bf, int K, int N,
                const float* __restrict__ xg,
                const int* __restrict__ stok_g, const float* __restrict__ sgate_g,
                u16* __restrict__ Hh, u16* __restrict__ Hl,
                float* __restrict__ outp)
{
    __shared__ __align__(16) u16 sAh[BM * LSTR];
    __shared__ __align__(16) u16 sAl[BM * LSTR];
    __shared__ __align__(16) u16 sBh[BN * LSTR];
    __shared__ __align__(16) u16 sBl[BN * LSTR];
    __shared__ int   srow_tok[BM * 2];
    __shared__ float srow_gate[BM * 2];

    const int tid  = threadIdx.x;
    const int lane = tid & 63;
    const int wave = tid >> 6;
    const int wm = (wave >> 1) * 64;
    const int wn = (wave & 1) * 64;
    const int M0 = blockIdx.y * BM;
    const int N0 = blockIdx.x * BN;

    if (AMODE == 1) {
        for (int i = tid; i < BM * 2; i += 256) {
            int row = M0 + (i >> 1);
            int g = row >> 5, c = row & 31;
            srow_tok[i] = stok_g[((size_t)g * SLOTS + c) * 2 + (i & 1)];
        }
        __syncthreads();
    }

    f32x4 acc[4][4];
#pragma unroll
    for (int mi = 0; mi < 4; mi++)
#pragma unroll
        for (int ni = 0; ni < 4; ni++) {
            acc[mi][ni].x = 0.f; acc[mi][ni].y = 0.f;
            acc[mi][ni].z = 0.f; acc[mi][ni].w = 0.f;
        }

    const int ar = tid >> 1;
    const int ac = (tid & 1) * 16;
    const int bk = tid >> 3;
    const int bn0 = tid & 7;

    for (int k0 = 0; k0 < K; k0 += BK) {
        if (AMODE == 0) {
            const float* src = Af + (size_t)(M0 + ar) * K + k0 + ac;
#pragma unroll
            for (int j = 0; j < 16; j += 4) {
                float4 v = *reinterpret_cast<const float4*>(src + j);
                float vv[4] = {v.x, v.y, v.z, v.w};
                u16 hh[4], ll[4];
#pragma unroll
                for (int q = 0; q < 4; q++) split2(vv[q], hh[q], ll[q]);
#pragma unroll
                for (int q = 0; q < 4; q += 2) {
                    *(u32*)&sAh[ar * LSTR + ac + j + q] = (u32)hh[q] | ((u32)hh[q + 1] << 16);
                    *(u32*)&sAl[ar * LSTR + ac + j + q] = (u32)ll[q] | ((u32)ll[q + 1] << 16);
                }
            }
        } else if (AMODE == 1) {
            int t0 = srow_tok[ar * 2], t1 = srow_tok[ar * 2 + 1];
            int g = (M0 + ar) >> 5;
            const float* x0 = xg + (size_t)(g * GROUP + (t0 < 0 ? 0 : t0)) * D_MODEL + k0 + ac;
            const float* x1 = xg + (size_t)(g * GROUP + (t1 < 0 ? 0 : t1)) * D_MODEL + k0 + ac;
#pragma unroll
            for (int j = 0; j < 16; j += 4) {
                float4 v0 = (t0 >= 0) ? *reinterpret_cast<const float4*>(x0 + j) : make_float4(0, 0, 0, 0);
                float4 v1 = (t1 >= 0) ? *reinterpret_cast<const float4*>(x1 + j) : make_float4(0, 0, 0, 0);
                float vv[4] = {v0.x + v1.x, v0.y + v1.y, v0.z + v1.z, v0.w + v1.w};
                u16 hh[4], ll[4];
#pragma unroll
                for (int q = 0; q < 4; q++) split2(vv[q], hh[q], ll[q]);
#pragma unroll
                for (int q = 0; q < 4; q += 2) {
                    *(u32*)&sAh[ar * LSTR + ac + j + q] = (u32)hh[q] | ((u32)hh[q + 1] << 16);
                    *(u32*)&sAl[ar * LSTR + ac + j + q] = (u32)ll[q] | ((u32)ll[q + 1] << 16);
                }
            }
        } else {
            const u16* sh = AhG + (size_t)(M0 + ar) * K + k0 + ac;
            const u16* sl = AlG + (size_t)(M0 + ar) * K + k0 + ac;
            *(uint4*)&sAh[ar * LSTR + ac]     = *(const uint4*)(sh);
            *(uint4*)&sAh[ar * LSTR + ac + 8] = *(const uint4*)(sh + 8);
            *(uint4*)&sAl[ar * LSTR + ac]     = *(const uint4*)(sl);
            *(uint4*)&sAl[ar * LSTR + ac + 8] = *(const uint4*)(sl + 8);
        }
        {
            const float* src = Bf + (size_t)(k0 + bk) * N + N0 + bn0;
#pragma unroll
            for (int j = 0; j < 16; j++) {
                float v = src[8 * j];
                u16 h, l; split2(v, h, l);
                sBh[(bn0 + 8 * j) * LSTR + bk] = h;
                sBl[(bn0 + 8 * j) * LSTR + bk] = l;
            }
        }
        __syncthreads();
        const int fr = lane & 15;
        const int kb = (lane >> 4) * 8;
        bf16x8 ah[4], al[4], bh[4], bl[4];
#pragma unroll
        for (int mi = 0; mi < 4; mi++) {
            ah[mi] = *(const bf16x8*)&sAh[(wm + mi * 16 + fr) * LSTR + kb];
            al[mi] = *(const bf16x8*)&sAl[(wm + mi * 16 + fr) * LSTR + kb];
        }
#pragma unroll
        for (int ni = 0; ni < 4; ni++) {
            bh[ni] = *(const bf16x8*)&sBh[(wn + ni * 16 + fr) * LSTR + kb];
            bl[ni] = *(const bf16x8*)&sBl[(wn + ni * 16 + fr) * LSTR + kb];
        }
#pragma unroll
        for (int mi = 0; mi < 4; mi++)
#pragma unroll
            for (int ni = 0; ni < 4; ni++) {
                acc[mi][ni] = __builtin_amdgcn_mfma_f32_16x16x32_bf16(ah[mi], bh[ni], acc[mi][ni], 0, 0, 0);
                acc[mi][ni] = __builtin_amdgcn_mfma_f32_16x16x32_bf16(ah[mi], bl[ni], acc[mi][ni], 0, 0, 0);
                acc[mi][ni] = __builtin_amdgcn_mfma_f32_16x16x32_bf16(al[mi], bh[ni], acc[mi][ni], 0, 0, 0);
            }
        __syncthreads();
    }

    if (EPI == 2) {
        for (int i = tid; i < BM * 2; i += 256) {
            int row = M0 + (i >> 1);
            int g = row >> 5, c = row & 31;
            size_t idx = ((size_t)g * SLOTS + c) * 2 + (i & 1);
            srow_tok[i] = stok_g[idx];
            srow_gate[i] = sgate_g[idx];
        }
        __syncthreads();
    }
    const int fr = lane & 15;
    const int fq = lane >> 4;
#pragma unroll
    for (int mi = 0; mi < 4; mi++)
#pragma unroll
        for (int ni = 0; ni < 4; ni++)
#pragma unroll
            for (int r = 0; r < 4; r++) {
                int ml = wm + mi * 16 + fq * 4 + r;
                int n  = N0 + wn + ni * 16 + fr;
                float v = acc[mi][ni][r];
                if (EPI == 0) {
                    v = gelu_tanh(v);
                    u16 h, l; split2(v, h, l);
                    size_t o = (size_t)(M0 + ml) * N + n;
                    Hh[o] = h; Hl[o] = l;
                } else if (EPI == 1) {
                    outp[(size_t)(M0 + ml) * N + n] = v;
                } else {
                    int g = (M0 + ml) >> 5;
                    int t0 = srow_tok[ml * 2], t1 = srow_tok[ml * 2 + 1];
                    if (t0 >= 0)
                        atomicAdd(&outp[(size_t)(g * GROUP + t0) * D_MODEL + n], srow_gate[ml * 2] * v);
                    if (t1 >= 0)
                        atomicAdd(&outp[(size_t)(g * GROUP + t1) * D_MODEL + n], srow_gate[ml * 2 + 1] * v);
                }
            }
}

// ---------- launch ----------
extern "C" void kernel_launch(void* const* d_in, const int* in_sizes, int n_in,
                              void* d_out, int out_size, void* d_ws, size_t ws_size,
                              hipStream_t stream) {
    const float* x    = (const float*)d_in[0];
    const float* gw   = (const float*)d_in[1];
    const float* gb   = (const float*)d_in[2];
    const float* keys = (const float*)d_in[3];
    const float* vals = (const float*)d_in[4];
    const float* sk   = (const float*)d_in[5];
    const float* sv   = (const float*)d_in[6];
    float* out = (float*)d_out;

    const size_t SLOT_BYTES = (size_t)NE * NGROUPS * SLOTS * 2 * 4;   // 262144 each
    // new-path workspace (~210 MB; previous 218 MB requirement was satisfied)
    const size_t NEED_NEW = 2 * SLOT_BYTES
                          + (size_t)NTOK * D_MODEL * 2          // Xs     33.5MB
                          + (size_t)NTOK * HIDDEN * 2           // Hsh   134.2MB (routed H aliases)
                          + (size_t)HIDDEN * D_MODEL * 2        // SKs     8.4MB
                          + (size_t)D_MODEL * HIDDEN * 2        // SVs     8.4MB
                          + (size_t)HIDDEN * D_MODEL * 2        // Ks_e    8.4MB
                          + (size_t)D_MODEL * HIDDEN * 2        // Vs_e    8.4MB
                          + (size_t)ROWS_E * D_MODEL * 2;       // Ar_e    8.4MB

    if (ws_size >= NEED_NEW) {
        char* w = (char*)d_ws;
        int*   slot_tok  = (int*)w;   w += SLOT_BYTES;
        float* slot_gate = (float*)w; w += SLOT_BYTES;
        u16* Xs   = (u16*)w; w += (size_t)NTOK * D_MODEL * 2;
        u16* Hsh  = (u16*)w; w += (size_t)NTOK * HIDDEN * 2;
        u16* SKs  = (u16*)w; w += (size_t)HIDDEN * D_MODEL * 2;
        u16* SVs  = (u16*)w; w += (size_t)D_MODEL * HIDDEN * 2;
        u16* Ks_e = (u16*)w; w += (size_t)HIDDEN * D_MODEL * 2;
        u16* Vs_e = (u16*)w; w += (size_t)D_MODEL * HIDDEN * 2;
        u16* Ar_e = (u16*)w; w += (size_t)ROWS_E * D_MODEL * 2;
        u16* Hr   = Hsh;   // routed hidden aliases shared hidden (consumed before reuse)

        gate_kernel<<<NGROUPS, GROUP, 0, stream>>>(x, gw, gb, slot_tok, slot_gate);
        cast_rows<<<(NTOK * D_MODEL) / (256 * 8), 256, 0, stream>>>(x, Xs);
        transp_cast<<<dim3(HIDDEN / 32, D_MODEL / 32), 256, 0, stream>>>(sk, SKs, D_MODEL, HIDDEN);
        transp_cast<<<dim3(D_MODEL / 32, HIDDEN / 32), 256, 0, stream>>>(sv, SVs, HIDDEN, D_MODEL);

        // shared expert, merged over all 16384 tokens
        gemm_bf16<0, 1><<<dim3(HIDDEN / 128, NTOK / 128), 256, 0, stream>>>(
            Xs, SKs, D_MODEL, HIDDEN, Hsh, nullptr, nullptr, nullptr);
        gemm_bf16<1, 1><<<dim3(D_MODEL / 128, NTOK / 128), 256, 0, stream>>>(
            Hsh, SVs, HIDDEN, D_MODEL, nullptr, out, nullptr, nullptr);

        // routed experts
        for (int e = 0; e < NE; e++) {
            const int* st = slot_tok + (size_t)e * NGROUPS * SLOTS * 2;
            const float* sg = slot_gate + (size_t)e * NGROUPS * SLOTS * 2;
            gather_cast<<<ROWS_E, 128, 0, stream>>>(x, st, Ar_e);
            transp_cast<<<dim3(HIDDEN / 32, D_MODEL / 32), 256, 0, stream>>>(
                keys + (size_t)e * D_MODEL * HIDDEN, Ks_e, D_MODEL, HIDDEN);
            transp_cast<<<dim3(D_MODEL / 32, HIDDEN / 32), 256, 0, stream>>>(
                vals + (size_t)e * HIDDEN * D_MODEL, Vs_e, HIDDEN, D_MODEL);
            gemm_bf16<0, 1><<<dim3(HIDDEN / 128, ROWS_E / 128), 256, 0, stream>>>(
                Ar_e, Ks_e, D_MODEL, HIDDEN, Hr, nullptr, nullptr, nullptr);
            gemm_bf16<2, 2><<<dim3(D_MODEL / 128, ROWS_E / 128, 2), 256, 0, stream>>>(
                Hr, Vs_e, HIDDEN, D_MODEL, nullptr, out, st, sg);
        }
    } else {
        // fallback: round-1 path (needs ~135MB), validated
        char* w = (char*)d_ws;
        int* slot_tok = (int*)w;      w += SLOT_BYTES;
        float* slot_gate = (float*)w; w += SLOT_BYTES;
        u16* Hh = (u16*)w;            w += (size_t)ROWS_E * HIDDEN * 2;
        u16* Hl = (u16*)w;            w += (size_t)ROWS_E * HIDDEN * 2;

        gate_kernel<<<NGROUPS, GROUP, 0, stream>>>(x, gw, gb, slot_tok, slot_gate);
        for (int ch = 0; ch < 4; ch++) {
            const float* Axc = x + (size_t)ch * 4096 * D_MODEL;
            float* outc = out + (size_t)ch * 4096 * D_MODEL;
            gemm_split<0, 0><<<dim3(HIDDEN / BN, 4096 / BM), 256, 0, stream>>>(
                Axc, nullptr, nullptr, sk, D_MODEL, HIDDEN,
                nullptr, nullptr, nullptr, Hh, Hl, nullptr);
            gemm_split<2, 1><<<dim3(D_MODEL / BN, 4096 / BM), 256, 0, stream>>>(
                nullptr, Hh, Hl, sv, HIDDEN, D_MODEL,
                nullptr, nullptr, nullptr, nullptr, nullptr, outc);
        }
        for (int e = 0; e < NE; e++) {
            const int* st = slot_tok + (size_t)e * NGROUPS * SLOTS * 2;
            const float* sg = slot_gate + (size_t)e * NGROUPS * SLOTS * 2;
            gemm_split<1, 0><<<dim3(HIDDEN / BN, ROWS_E / BM), 256, 0, stream>>>(
                nullptr, nullptr, nullptr, keys + (size_t)e * D_MODEL * HIDDEN, D_MODEL, HIDDEN,
                x, st, nullptr, Hh, Hl, nullptr);
            gemm_split<2, 2><<<dim3(D_MODEL / BN, ROWS_E / BM), 256, 0, stream>>>(
                nullptr, Hh, Hl, vals + (size_t)e * HIDDEN * D_MODEL, HIDDEN, D_MODEL,
                nullptr, st, sg, nullptr, nullptr, out);
        }
    }
}